// Round 1
// baseline (3512.623 us; speedup 1.0000x reference)
//
#include <hip/hip_runtime.h>
#include <math.h>

// ---------------- constants ----------------
#define T_STEPS 50
#define NB 512          // S*B batch rows
#define D_DIM 128
#define H_DIM 24
#define C_DIM 32
#define ELEMS (D_DIM*H_DIM)   // 3072
#define RS2 0.70710678118654752f
#define INV_SQRT_L 0.40824829046386302f

struct SchedArg { float cx0[T_STEPS], cxt[T_STEPS], sig[T_STEPS], s1m[T_STEPS], isab[T_STEPS]; };
struct FreqArg  { double f[64]; };

// ---------------- kernel A: Student-t marginal fit ----------------
__global__ __launch_bounds__(256) void fit_kernel(const float* __restrict__ xh,
                                                  float* __restrict__ loc,
                                                  float* __restrict__ scalef) {
    int gid = blockIdx.x * 256 + threadIdx.x;       // 0..4095  (b*128+d)
    int b = gid >> 7, d = gid & 127;
    const float* p = xh + (size_t)b * 192 * 128 + d;
    float s = 0.f;
    for (int t = 0; t < 192; ++t) s += p[t * 128];
    float m = s * (1.0f / 192.0f);
    float v = 0.f;
    for (int t = 0; t < 192; ++t) {
        float c = p[t * 128] - m; c *= c;
        v = (t == 0) ? c : 0.94f * v + (1.0f - 0.94f) * c;
    }
    float sc = sqrtf(v * 0.5f);                      // (df-2)/df = 0.5
    loc[gid] = m;
    scalef[gid] = fmaxf(sc, 1e-5f);
}

// ---------------- kernel B: per-t diffusion embedding -> cond[6][32] ----------------
__global__ __launch_bounds__(256) void temb_kernel(
    const float* __restrict__ w1, const float* __restrict__ b1,
    const float* __restrict__ w2, const float* __restrict__ b2,
    const float* __restrict__ wt, const float* __restrict__ bt,
    float* __restrict__ cond_all, FreqArg fq) {
    int t = blockIdx.x;           // 0..49
    int tid = threadIdx.x;
    __shared__ float pe[128], te1[512], te2[512];
    if (tid < 64) {
        double e = (double)t * fq.f[tid];
        pe[tid]      = (float)sin(e);
        pe[tid + 64] = (float)cos(e);
    }
    __syncthreads();
    for (int j = tid; j < 512; j += 256) {
        float acc = b1[j];
        for (int k = 0; k < 128; ++k) acc += pe[k] * w1[k * 512 + j];
        te1[j] = acc / (1.f + expf(-acc));           // silu
    }
    __syncthreads();
    for (int j = tid; j < 512; j += 256) {
        float acc = b2[j];
        for (int k = 0; k < 512; ++k) acc += te1[k] * w2[k * 512 + j];
        te2[j] = acc / (1.f + expf(-acc));
    }
    __syncthreads();
    if (tid < 192) {              // l = tid/32, c = tid%32
        int l = tid >> 5, c = tid & 31;
        float acc = bt[l * 32 + c];
        const float* w = wt + (size_t)l * 512 * 32 + c;
        for (int k = 0; k < 512; ++k) acc += te2[k] * w[k * 32];
        cond_all[t * 192 + tid] = acc;
    }
}

// ---------------- staging helper: global [ROWS][COLS] -> LDS [ROWS][COLS+1] ----------------
template <int ROWS, int COLS>
__device__ inline void stage_pad(const float* __restrict__ g, float* dst, int tid) {
    constexpr int N = ROWS * COLS;
    for (int idx = tid; idx < N; idx += 256) {
        int r = idx / COLS;
        dst[r * (COLS + 1) + (idx - r * COLS)] = g[idx];
    }
}

// ---------------- kernel C: full 50-step diffusion + output transform ----------------
__global__ __launch_bounds__(256, 2) void diffusion_kernel(
    const float* __restrict__ z_init, const float* __restrict__ noise,
    const float* __restrict__ w_in,   const float* __restrict__ b_in,
    const float* __restrict__ lyr_wdil, const float* __restrict__ lyr_bdil,
    const float* __restrict__ lyr_wout, const float* __restrict__ lyr_bout,
    const float* __restrict__ w_o1, const float* __restrict__ b_o1,
    const float* __restrict__ w_o2, const float* __restrict__ b_o2,
    const float* __restrict__ cond_all, const float* __restrict__ loc,
    const float* __restrict__ scalef, float* __restrict__ out, SchedArg sc) {

    __shared__ float xs[ELEMS];        // x state [128][24]
    __shared__ float hs[768];          // h [32][24]
    __shared__ float skips[768];       // skip [32][24]
    __shared__ float convs[1536];      // conv out [64][24]; rows 0..31 reused for act
    __shared__ float ssb[768];         // hc / s buffer [32][24]
    __shared__ float winb[32 * 129];   // padded W_in (staged once)
    __shared__ float wbuf[8320];       // staging: wdil[64][97]+wout[64][33] | w_o1[32][33]+w_o2[128][33]

    const int tid = threadIdx.x;
    const int bb  = blockIdx.x;        // batch row 0..511

    for (int idx = tid; idx < ELEMS; idx += 256)
        xs[idx] = z_init[(size_t)bb * ELEMS + idx];
    stage_pad<32, 128>(w_in, winb, tid);
    __syncthreads();

    const int sub  = tid & 7;          // 8 h-groups of 3
    const int grp  = tid >> 3;         // 0..31
    const int hh0  = 3 * sub;

    for (int step = 0; step < T_STEPS; ++step) {
        const int t = 49 - step;

        // ---- phase 1: h = relu(W_in @ x + b_in); skip = 0 ----
        {
            const int c = grp;
            float bv = b_in[c];
            float a0 = bv, a1 = bv, a2 = bv;
            const float* wr = winb + c * 129;
            for (int k = 0; k < 128; ++k) {
                float w = wr[k];
                const float* xr = xs + k * 24 + hh0;
                a0 += w * xr[0]; a1 += w * xr[1]; a2 += w * xr[2];
            }
            int base = c * 24 + hh0;
            hs[base + 0] = fmaxf(a0, 0.f);
            hs[base + 1] = fmaxf(a1, 0.f);
            hs[base + 2] = fmaxf(a2, 0.f);
            skips[base + 0] = 0.f; skips[base + 1] = 0.f; skips[base + 2] = 0.f;
        }
        __syncthreads();

        // ---- residual layers ----
        for (int li = 0; li < 6; ++li) {
            stage_pad<64, 96>(lyr_wdil + (size_t)li * 6144, wbuf, tid);
            stage_pad<64, 32>(lyr_wout + (size_t)li * 2048, wbuf + 6208, tid);
            // hc = h + cond  (same-thread elements as writers is not guaranteed -> covered by sync)
            {
                float cv = cond_all[t * 192 + li * 32 + grp];
                int base = grp * 24 + hh0;
                ssb[base + 0] = hs[base + 0] + cv;
                ssb[base + 1] = hs[base + 1] + cv;
                ssb[base + 2] = hs[base + 2] + cv;
            }
            __syncthreads();   // S1: weights staged + hc ready

            // dilated conv, 2 o x 3 h per thread
            const int d = 1 << li;
            {
                const int o0 = 2 * grp;
                float bd0 = lyr_bdil[li * 64 + o0], bd1 = lyr_bdil[li * 64 + o0 + 1];
                float a00 = bd0, a01 = bd0, a02 = bd0;
                float a10 = bd1, a11 = bd1, a12 = bd1;
                const int offk[3] = { hh0 - d, hh0, hh0 + d };
                const float* w0 = wbuf + o0 * 97;
                const float* w1 = w0 + 97;
                for (int c = 0; c < 32; ++c) {
                    const float* row = ssb + c * 24;
                    const float* wc0 = w0 + c * 3;
                    const float* wc1 = w1 + c * 3;
#pragma unroll
                    for (int k = 0; k < 3; ++k) {
                        float wa = wc0[k], wb = wc1[k];
                        int jb = offk[k];
#pragma unroll
                        for (int jj = 0; jj < 3; ++jj) {
                            int j = jb + jj;
                            float r = (j >= 0 && j < 24) ? row[j] : 0.f;
                            if (jj == 0) { a00 += wa * r; a10 += wb * r; }
                            else if (jj == 1) { a01 += wa * r; a11 += wb * r; }
                            else { a02 += wa * r; a12 += wb * r; }
                        }
                    }
                }
                int b0 = o0 * 24 + hh0;
                convs[b0 + 0] = a00; convs[b0 + 1] = a01; convs[b0 + 2] = a02;
                convs[b0 + 24] = a10; convs[b0 + 25] = a11; convs[b0 + 26] = a12;
            }
            __syncthreads();   // S2

            // act: gate=rows 0..31, filt=rows 32..63 ; act stored into rows 0..31
#pragma unroll
            for (int p = 0; p < 3; ++p) {
                int e = tid + p * 256;
                float g = convs[e], f = convs[768 + e];
                convs[e] = tanhf(f) * (1.f / (1.f + expf(-g)));
            }
            __syncthreads();   // S3

            // out-proj: res -> h, sk -> skip ; 2 o x 3 h per thread
            {
                const int o0 = 2 * grp;
                float b0v = lyr_bout[li * 64 + o0], b1v = lyr_bout[li * 64 + o0 + 1];
                float a00 = b0v, a01 = b0v, a02 = b0v;
                float a10 = b1v, a11 = b1v, a12 = b1v;
                const float* w0 = wbuf + 6208 + o0 * 33;
                const float* w1 = w0 + 33;
                for (int c = 0; c < 32; ++c) {
                    float wa = w0[c], wb = w1[c];
                    const float* row = convs + c * 24 + hh0;
                    float r0 = row[0], r1 = row[1], r2 = row[2];
                    a00 += wa * r0; a01 += wa * r1; a02 += wa * r2;
                    a10 += wb * r0; a11 += wb * r1; a12 += wb * r2;
                }
                if (o0 < 32) {
                    int base = o0 * 24 + hh0;
                    hs[base + 0]  = (hs[base + 0]  + a00) * RS2;
                    hs[base + 1]  = (hs[base + 1]  + a01) * RS2;
                    hs[base + 2]  = (hs[base + 2]  + a02) * RS2;
                    hs[base + 24] = (hs[base + 24] + a10) * RS2;
                    hs[base + 25] = (hs[base + 25] + a11) * RS2;
                    hs[base + 26] = (hs[base + 26] + a12) * RS2;
                } else {
                    int base = (o0 - 32) * 24 + hh0;
                    skips[base + 0]  += a00; skips[base + 1]  += a01; skips[base + 2]  += a02;
                    skips[base + 24] += a10; skips[base + 25] += a11; skips[base + 26] += a12;
                }
            }
            __syncthreads();   // S4
        }

        // ---- skip head: s = relu(W_o1 @ (skip/sqrt(6)) + b_o1) ----
        stage_pad<32, 32>(w_o1, wbuf, tid);
        stage_pad<128, 32>(w_o2, wbuf + 1056, tid);
        __syncthreads();
        {
            const int c = grp;
            float a0 = 0.f, a1 = 0.f, a2 = 0.f;
            const float* wr = wbuf + c * 33;
            for (int c2 = 0; c2 < 32; ++c2) {
                float w = wr[c2];
                const float* row = skips + c2 * 24 + hh0;
                a0 += w * row[0]; a1 += w * row[1]; a2 += w * row[2];
            }
            float bv = b_o1[c];
            int base = c * 24 + hh0;
            ssb[base + 0] = fmaxf(bv + INV_SQRT_L * a0, 0.f);
            ssb[base + 1] = fmaxf(bv + INV_SQRT_L * a1, 0.f);
            ssb[base + 2] = fmaxf(bv + INV_SQRT_L * a2, 0.f);
        }
        __syncthreads();

        // ---- eps = W_o2 @ s + b_o2 fused with DDPM update ----
        {
            const float cx0 = sc.cx0[t], cxt = sc.cxt[t], sig = sc.sig[t];
            const float s1m = sc.s1m[t], isab = sc.isab[t];
            const float* nzp = noise + ((size_t)step * NB + bb) * ELEMS;
            const int dd0 = grp * 4;
            float e0[3], e1[3], e2[3], e3[3];
#pragma unroll
            for (int j = 0; j < 3; ++j) { e0[j] = b_o2[dd0]; e1[j] = b_o2[dd0+1]; e2[j] = b_o2[dd0+2]; e3[j] = b_o2[dd0+3]; }
            const float* wr = wbuf + 1056 + dd0 * 33;
            for (int c = 0; c < 32; ++c) {
                float w0 = wr[c], w1 = wr[33 + c], w2 = wr[66 + c], w3 = wr[99 + c];
                const float* row = ssb + c * 24 + hh0;
                float r0 = row[0], r1 = row[1], r2 = row[2];
                e0[0] += w0 * r0; e0[1] += w0 * r1; e0[2] += w0 * r2;
                e1[0] += w1 * r0; e1[1] += w1 * r1; e1[2] += w1 * r2;
                e2[0] += w2 * r0; e2[1] += w2 * r1; e2[2] += w2 * r2;
                e3[0] += w3 * r0; e3[1] += w3 * r1; e3[2] += w3 * r2;
            }
#pragma unroll
            for (int i = 0; i < 4; ++i) {
                float ei0 = (i==0)?e0[0]:(i==1)?e1[0]:(i==2)?e2[0]:e3[0];
                float ei1 = (i==0)?e0[1]:(i==1)?e1[1]:(i==2)?e2[1]:e3[1];
                float ei2 = (i==0)?e0[2]:(i==1)?e1[2]:(i==2)?e2[2]:e3[2];
                int base = (dd0 + i) * 24 + hh0;
#pragma unroll
                for (int j = 0; j < 3; ++j) {
                    float ev = (j==0)?ei0:(j==1)?ei1:ei2;
                    int idx = base + j;
                    float xv = xs[idx];
                    float x0 = (xv - s1m * ev) * isab;
                    x0 = fminf(fmaxf(x0, -1.f), 1.f);
                    xs[idx] = cx0 * x0 + cxt * xv + sig * nzp[idx];
                }
            }
        }
        __syncthreads();
    }

    // ---- epilogue: Gaussian -> Student-t4 marginal, write [S,B,H,D] ----
    {
        const int b = bb & 31;
#pragma unroll
        for (int p = 0; p < 12; ++p) {
            int e = tid + p * 256;
            int dd = e / 24, hh = e - dd * 24;
            float z = xs[e];
            float u = 0.5f * (1.f + erff(z * RS2));
            u = fminf(fmaxf(u, 1e-6f), 1.f - 1e-6f);
            float a4 = 4.f * u * (1.f - u);
            a4 = fminf(fmaxf(a4, 1e-12f), 1.f);
            float r = sqrtf(a4);
            float q = 2.f * sqrtf(fmaxf(cosf(acosf(r) * (1.f / 3.f)) / r - 1.f, 0.f));
            float tstd = (u < 0.5f) ? -q : q;
            out[((size_t)bb * 24 + hh) * 128 + dd] = loc[b * 128 + dd] + scalef[b * 128 + dd] * tstd;
        }
    }
}

// ---------------- host ----------------
extern "C" void kernel_launch(void* const* d_in, const int* in_sizes, int n_in,
                              void* d_out, int out_size, void* d_ws, size_t ws_size,
                              hipStream_t stream) {
    const float* x_hist  = (const float*)d_in[0];
    const float* z_init  = (const float*)d_in[1];
    const float* noise   = (const float*)d_in[2];
    const float* w_in    = (const float*)d_in[3];
    const float* b_in    = (const float*)d_in[4];
    const float* temb_w1 = (const float*)d_in[5];
    const float* temb_b1 = (const float*)d_in[6];
    const float* temb_w2 = (const float*)d_in[7];
    const float* temb_b2 = (const float*)d_in[8];
    const float* lyr_wt  = (const float*)d_in[9];
    const float* lyr_bt  = (const float*)d_in[10];
    const float* lyr_wdil= (const float*)d_in[11];
    const float* lyr_bdil= (const float*)d_in[12];
    const float* lyr_wout= (const float*)d_in[13];
    const float* lyr_bout= (const float*)d_in[14];
    const float* w_o1    = (const float*)d_in[15];
    const float* b_o1    = (const float*)d_in[16];
    const float* w_o2    = (const float*)d_in[17];
    const float* b_o2    = (const float*)d_in[18];
    float* out = (float*)d_out;

    float* loc      = (float*)d_ws;            // 4096
    float* scalef   = loc + 4096;              // 4096
    float* cond_all = scalef + 4096;           // 50*192 = 9600

    // DDPM schedule in double, rounded to f32
    SchedArg sa;
    double abar = 1.0;
    for (int t = 0; t < T_STEPS; ++t) {
        double beta  = 1e-4 + (0.1 - 1e-4) * ((double)t / 49.0);
        double alpha = 1.0 - beta;
        double abprev = abar;
        abar *= alpha;
        sa.cx0[t]  = (float)(beta * sqrt(abprev) / (1.0 - abar));
        sa.cxt[t]  = (float)((1.0 - abprev) * sqrt(alpha) / (1.0 - abar));
        double pv  = beta * (1.0 - abprev) / (1.0 - abar);
        sa.sig[t]  = (t > 0) ? (float)sqrt(pv) : 0.f;
        sa.s1m[t]  = (float)sqrt(1.0 - abar);
        sa.isab[t] = (float)(1.0 / sqrt(abar));
    }
    FreqArg fa;
    for (int j = 0; j < 64; ++j) fa.f[j] = pow(10.0, (double)j * 4.0 / 63.0);

    fit_kernel<<<16, 256, 0, stream>>>(x_hist, loc, scalef);
    temb_kernel<<<T_STEPS, 256, 0, stream>>>(temb_w1, temb_b1, temb_w2, temb_b2,
                                             lyr_wt, lyr_bt, cond_all, fa);
    diffusion_kernel<<<NB, 256, 0, stream>>>(z_init, noise, w_in, b_in,
                                             lyr_wdil, lyr_bdil, lyr_wout, lyr_bout,
                                             w_o1, b_o1, w_o2, b_o2,
                                             cond_all, loc, scalef, out, sa);
}